// Round 22
// baseline (635.533 us; speedup 1.0000x reference)
//
#include <hip/hip_runtime.h>
#include <math.h>

#define NT 256
#define NTS 128   // sage_layer: 2 waves, 16-node tile

typedef unsigned short ushort_t;
typedef unsigned int uint_t;
typedef __attribute__((ext_vector_type(8))) short bf16x8;
typedef __attribute__((ext_vector_type(4))) float f32x4;

__device__ __forceinline__ int rli(int v, int l) {
    return __builtin_amdgcn_readlane(v, l);
}
__device__ __forceinline__ int imax(int a, int b) { return a > b ? a : b; }
__device__ __forceinline__ int imin(int a, int b) { return a < b ? a : b; }

__device__ __forceinline__ ushort_t f2bf_rne(float f) {
    uint_t u = __float_as_uint(f);
    uint_t r = u + 0x7FFF + ((u >> 16) & 1);
    return (ushort_t)(r >> 16);
}
__device__ __forceinline__ float bf2f(ushort_t b) {
    return __uint_as_float(((uint_t)b) << 16);
}
__device__ __forceinline__ float rlf(float v, int l) {
    return __int_as_float(__builtin_amdgcn_readlane(__float_as_int(v), l));
}

// async global->LDS copy: 4 B/lane, per-lane global src, wave-uniform LDS base
__device__ __forceinline__ void async_copy4(const void* g, void* l) {
    __builtin_amdgcn_global_load_lds(
        (__attribute__((address_space(1))) unsigned int*)(unsigned long long)g,
        (__attribute__((address_space(3))) unsigned int*)l,
        4, 0, 0);
}

// select idx from 4 lane-vectors by linear position (0..255)
__device__ __forceinline__ int selidx(int pos, int e0, int e1, int e2, int e3) {
    int l = pos & 63;
    int r0 = rli(e0, l), r1 = rli(e1, l), r2 = rli(e2, l), r3 = rli(e3, l);
    int j = pos >> 6;
    return j == 0 ? r0 : (j == 1 ? r1 : (j == 2 ? r2 : r3));
}

// ---------------- CSR build ----------------

__global__ void zero_i32(int* __restrict__ p, int n) {
    int t = blockIdx.x * blockDim.x + threadIdx.x;
    if (t < n) p[t] = 0;
}

__global__ void hist_dst(int* __restrict__ cnt, const int* __restrict__ dst, int n_edges) {
    int e = blockIdx.x * blockDim.x + threadIdx.x;
    if (e < n_edges) atomicAdd(&cnt[dst[e]], 1);
}

__global__ void scan_blocks(const int* __restrict__ cnt, int* __restrict__ bsum, int n) {
    __shared__ int s[NT];
    int i = blockIdx.x * NT + threadIdx.x;
    s[threadIdx.x] = (i < n) ? cnt[i] : 0;
    __syncthreads();
    for (int off = NT / 2; off > 0; off >>= 1) {
        if (threadIdx.x < off) s[threadIdx.x] += s[threadIdx.x + off];
        __syncthreads();
    }
    if (threadIdx.x == 0) bsum[blockIdx.x] = s[0];
}

__global__ void scan_bsum(const int* __restrict__ bsum, int* __restrict__ boff,
                          int nb, int* __restrict__ row_off, int n) {
    __shared__ int s[1024];
    int tid = threadIdx.x;
    int v = (tid < nb) ? bsum[tid] : 0;
    s[tid] = v;
    __syncthreads();
    for (int off = 1; off < 1024; off <<= 1) {
        int t = (tid >= off) ? s[tid - off] : 0;
        __syncthreads();
        s[tid] += t;
        __syncthreads();
    }
    if (tid < nb) boff[tid] = s[tid] - v;
    if (tid == nb - 1) row_off[n] = s[tid];
}

__global__ void scan_final(const int* __restrict__ cnt, const int* __restrict__ boff,
                           int* __restrict__ row_off, int* __restrict__ cursor, int n) {
    __shared__ int s[NT];
    int i = blockIdx.x * NT + threadIdx.x;
    int v = (i < n) ? cnt[i] : 0;
    s[threadIdx.x] = v;
    __syncthreads();
    for (int off = 1; off < NT; off <<= 1) {
        int t = (threadIdx.x >= off) ? s[threadIdx.x - off] : 0;
        __syncthreads();
        s[threadIdx.x] += t;
        __syncthreads();
    }
    if (i < n) {
        int ex = boff[blockIdx.x] + s[threadIdx.x] - v;
        row_off[i] = ex;
        cursor[i] = ex;
    }
}

__global__ void edge_scatter(int* __restrict__ csr_src, int* __restrict__ cursor,
                             const int* __restrict__ src, const int* __restrict__ dst,
                             int n_edges) {
    int e = blockIdx.x * blockDim.x + threadIdx.x;
    if (e < n_edges) {
        int p = atomicAdd(&cursor[dst[e]], 1);
        csr_src[p] = src[e];
    }
}

// ---------------- prep kernels ----------------

__global__ void f2bf_kern(ushort_t* __restrict__ o, const float* __restrict__ in, int n) {
    int t = blockIdx.x * blockDim.x + threadIdx.x;
    if (t < n) o[t] = f2bf_rne(in[t]);
}

// Pack combined weights into MFMA B-fragment order, bf16 (see r18).
__global__ void pack_w(ushort_t* __restrict__ packed, const float* __restrict__ Wl,
                       const float* __restrict__ Wr) {
    int t = blockIdx.x * blockDim.x + threadIdx.x;
    if (t < 8192) {
        int i = t & 7;
        int lane = (t >> 3) & 63;
        int nt = (t >> 9) & 3;
        int ks = t >> 11;
        int k = ks * 32 + ((lane >> 4) << 3) + i;
        int f = nt * 16 + (lane & 15);
        float w = (k < 64) ? Wl[f * 64 + k] : Wr[f * 64 + (k - 64)];
        packed[t] = f2bf_rne(w);
    }
}

// ---------------- pooling helpers ----------------

__global__ void pool_init(float* __restrict__ pooled, int n) {
    int t = blockIdx.x * blockDim.x + threadIdx.x;
    if (t < n) pooled[t] = -INFINITY;
}

__device__ __forceinline__ void atomicMaxFloat(float* addr, float value) {
    if (value >= 0.0f)
        atomicMax((int*)addr, __float_as_int(value));
    else
        atomicMin((unsigned int*)addr, (unsigned int)__float_as_int(value));
}

// ---------------- fused SAGE layer: async-ring gather + MFMA dense ----------------
// Per wave: 32-slot x 256B LDS ring, fixed 16 slots/node (2 edges/slot:
// lanes 0-31 row A, 32-63 row B via per-lane global_load_lds addresses).
// Steady state: s_waitcnt vmcnt(31) -> consume slot (issued 32 ago, retired
// by in-order rule) -> issue node n+2's slot. No VGPR-held loads -> ~32
// outstanding VMEM per wave vs compiler's 8. Rare nodes (deg>32 or wave edge
// span>256) recomputed synchronously after final drain. Dense: r20 MFMA.
__global__ __launch_bounds__(NTS, 8) void sage_layer(
    ushort_t* __restrict__ out_bf, float* __restrict__ pooled,
    const ushort_t* __restrict__ hb_in,
    const int* __restrict__ row_off, const int* __restrict__ csr_src,
    const int* __restrict__ batch,
    const ushort_t* __restrict__ pw,
    const float* __restrict__ bl,
    int n_nodes, int n_edges, int do_pool) {
    __shared__ ushort_t A[16 * 136];
    __shared__ uint_t RING[2][2048];  // per wave: 32 slots x 64 words (8KB)
    int tid = threadIdx.x;
    int lane = tid & 63;
    int v = tid >> 6;  // wave 0..1
    int g0 = blockIdx.x * 16 + v * 8;
    int l31 = lane & 31;

    // row offsets for the wave's 8 nodes (+1)
    int roidx = imin(g0 + imin(lane, 8), n_nodes);
    int ro = row_off[roidx];
    int eb = rli(ro, 0);
    int emax = n_edges - 1;

    // idx lane-vectors covering wave edge span [eb, eb+256)
    int ev0 = csr_src[imin(eb + lane, emax)];
    int ev1 = csr_src[imin(eb + 64 + lane, emax)];
    int ev2 = csr_src[imin(eb + 128 + lane, emax)];
    int ev3 = csr_src[imin(eb + 192 + lane, emax)];

    // prologue: stage hv rows into A cols 64-127 (and zero invalid nodes)
    for (int n = 0; n < 8; ++n) {
        int g = g0 + n;
        int row = v * 8 + n;
        uint_t hw = 0;
        if (g < n_nodes)
            hw = *(const uint_t*)&hb_in[((size_t)g << 6) + 2 * l31];
        *(uint_t*)&A[row * 136 + 64 + 2 * l31] = hw;
    }
    // drain so the pipeline's VMEM stream is pure global_load_lds
    asm volatile("s_waitcnt vmcnt(0)" ::: "memory");

#define ISSUE(BN, DN, BANK, S)                                                \
    {                                                                         \
        int dc_ = imin((DN), 32);                                             \
        int lastp_ = imax(dc_ - 1, 0);                                        \
        int p0_ = imin(2 * (S), lastp_);                                      \
        int p1_ = imin(2 * (S) + 1, lastp_);                                  \
        int pos0_ = imin((BN) - eb + p0_, 255);                               \
        int pos1_ = imin((BN) - eb + p1_, 255);                               \
        int iA_ = selidx(pos0_, ev0, ev1, ev2, ev3);                          \
        int iB_ = selidx(pos1_, ev0, ev1, ev2, ev3);                          \
        int isel_ = (lane < 32) ? iA_ : iB_;                                  \
        const char* src_ = (const char*)hb_in +                               \
            (((size_t)(unsigned)isel_) << 7) + ((size_t)l31 << 2);            \
        async_copy4(src_, &RING[v][(BANK) * 1024 + (S) * 64]);                \
    }

    // prologue issues: nodes 0 (bank 0) and 1 (bank 1)
    {
        int b0 = rli(ro, 0), d0v = rli(ro, 1) - b0;
        for (int s = 0; s < 16; ++s) ISSUE(b0, d0v, 0, s);
        int b1 = rli(ro, 1), d1v = rli(ro, 2) - b1;
        for (int s = 0; s < 16; ++s) ISSUE(b1, d1v, 1, s);
    }

    // main pipeline: consume node n, issue node n+2 (dummy source=7 past end)
    for (int n = 0; n < 8; ++n) {
        int bn = rli(ro, n);
        int dn = rli(ro, n + 1) - bn;
        int m = imin(n + 2, 7);
        int bm = rli(ro, m);
        int dm = rli(ro, m + 1) - bm;
        int bank = n & 1;
        int dc = imin(dn, 32);
        float accLo = 0.f, accHi = 0.f;
        for (int s = 0; s < 16; ++s) {
            asm volatile("s_waitcnt vmcnt(31)" ::: "memory");
            const uint_t* sl = &RING[v][bank * 1024 + s * 64];
            uint_t aw = sl[l31];
            uint_t bw = sl[32 + l31];
            float fa = (2 * s < dc) ? 1.f : 0.f;
            float fb = (2 * s + 1 < dc) ? 1.f : 0.f;
            accLo += fa * __uint_as_float(aw << 16);
            accHi += fa * __uint_as_float(aw & 0xffff0000u);
            accLo += fb * __uint_as_float(bw << 16);
            accHi += fb * __uint_as_float(bw & 0xffff0000u);
            ISSUE(bm, dm, bank, s);
        }
        float inv = 1.0f / (float)imax(dn, 1);
        uint_t mw = (uint_t)f2bf_rne(accLo * inv) |
                    ((uint_t)f2bf_rne(accHi * inv) << 16);
        *(uint_t*)&A[(v * 8 + n) * 136 + 2 * l31] = mw;
    }
    asm volatile("s_waitcnt vmcnt(0)" ::: "memory");

    // rare slow path: deg>32 or wave edge span >256 -> recompute synchronously
    for (int n = 0; n < 8; ++n) {
        int bn = rli(ro, n);
        int en = rli(ro, n + 1);
        int dn = en - bn;
        bool flag = (dn > 32) || ((bn - eb + imin(dn, 32)) > 256);
        int g = g0 + n;
        if (flag && g < n_nodes) {
            float aLo = 0.f, aHi = 0.f;
            for (int e = bn; e < en; ++e) {
                int idx = csr_src[e];
                uint_t hw = *(const uint_t*)&hb_in[((size_t)idx << 6) + 2 * l31];
                aLo += __uint_as_float(hw << 16);
                aHi += __uint_as_float(hw & 0xffff0000u);
            }
            float inv = 1.0f / (float)imax(dn, 1);
            uint_t mw = (uint_t)f2bf_rne(aLo * inv) |
                        ((uint_t)f2bf_rne(aHi * inv) << 16);
            *(uint_t*)&A[(v * 8 + n) * 136 + 2 * l31] = mw;
        }
    }
#undef ISSUE
    __syncthreads();

    // ---- phase 2: MFMA dense (r20 verbatim) ----
    int a_row = lane & 15;
    int kbase = (lane >> 4) << 3;
#pragma unroll
    for (int p = 0; p < 2; ++p) {
        int nt = v * 2 + p;
        f32x4 acc = {0.f, 0.f, 0.f, 0.f};
#pragma unroll
        for (int ks = 0; ks < 4; ++ks) {
            bf16x8 af = *reinterpret_cast<const bf16x8*>(&A[a_row * 136 + ks * 32 + kbase]);
            bf16x8 bf = *reinterpret_cast<const bf16x8*>(&pw[(((ks << 2) + nt) * 64 + lane) << 3]);
            acc = __builtin_amdgcn_mfma_f32_16x16x32_bf16(af, bf, acc, 0, 0, 0);
        }
        int c = nt * 16 + (lane & 15);
        float bias = bl[c];
        int rbase = blockIdx.x * 16 + ((lane >> 4) << 2);
#pragma unroll
        for (int j = 0; j < 4; ++j) {
            int g = rbase + j;
            if (g < n_nodes) {
                float o = tanhf(acc[j] + bias);
                if (do_pool) {
                    atomicMaxFloat(&pooled[(size_t)batch[g] * 64 + c], o);
                } else {
                    out_bf[(size_t)g * 64 + c] = f2bf_rne(o);
                }
            }
        }
    }
}

// ---------------- MLP head ----------------
__global__ void head(float* __restrict__ out, const float* __restrict__ pooled,
                     const float* __restrict__ W1, const float* __restrict__ b1,
                     const float* __restrict__ W2, const float* __restrict__ b2) {
    __shared__ float W1T[64][64];
    int tid = threadIdx.x;
    for (int t = tid; t < 4096; t += NT) {
        int f = t >> 6, k = t & 63;
        W1T[k][f] = W1[t];
    }
    __syncthreads();

    int lane = tid & 63;
    int g = blockIdx.x * (NT >> 6) + (tid >> 6);
    float v = pooled[(size_t)g * 64 + lane];
    float bias = b1[lane];
#pragma unroll
    for (int it = 0; it < 3; ++it) {
        float acc = bias;
#pragma unroll
        for (int k = 0; k < 64; ++k) {
            acc += rlf(v, k) * W1T[k][lane];
        }
        v = tanhf(acc);
    }
#pragma unroll
    for (int j = 0; j < 3; ++j) {
        float p = v * W2[j * 64 + lane];
#pragma unroll
        for (int off = 32; off >= 1; off >>= 1) p += __shfl_xor(p, off);
        if (lane == 0) out[g * 3 + j] = p + b2[j];
    }
}

// ---------------- launch ----------------

extern "C" void kernel_launch(void* const* d_in, const int* in_sizes, int n_in,
                              void* d_out, int out_size, void* d_ws, size_t ws_size,
                              hipStream_t stream) {
    const float* x   = (const float*)d_in[0];
    const float* Wl0 = (const float*)d_in[1];
    const float* Wr0 = (const float*)d_in[2];
    const float* bl0 = (const float*)d_in[3];
    const float* Wl  = (const float*)d_in[4];
    const float* Wr  = (const float*)d_in[5];
    const float* bl  = (const float*)d_in[6];
    const float* W1  = (const float*)d_in[7];
    const float* b1  = (const float*)d_in[8];
    const float* W2  = (const float*)d_in[9];
    const float* b2  = (const float*)d_in[10];
    const int* ei    = (const int*)d_in[11];
    const int* batch = (const int*)d_in[12];

    int n_nodes = in_sizes[0] / 64;
    int n_edges = in_sizes[11] / 2;
    const int* src = ei;
    const int* dst = ei + n_edges;

    int nb = (n_nodes + NT - 1) / NT;
    size_t nfeat = (size_t)n_nodes * 64;

    int* csr_src  = (int*)d_ws;                           // n_edges
    int* row_off  = csr_src + n_edges;                    // n_nodes+1
    int* cursor   = row_off + (n_nodes + 1);              // n_nodes
    int* cnt      = cursor + n_nodes;                     // n_nodes
    int* bsum     = cnt + n_nodes;                        // nb
    int* boff     = bsum + nb;                            // nb
    float* pooled = (float*)(boff + nb);                  // 128*64
    ushort_t* pw0 = (ushort_t*)(pooled + 128 * 64);       // 8192
    ushort_t* pw  = pw0 + 8192;                           // 8192
    ushort_t* bfX = pw + 8192;                            // nfeat
    ushort_t* bfA = bfX + nfeat;                          // nfeat
    ushort_t* bfB = bfA + nfeat;                          // nfeat

    int eblk = (n_edges + NT - 1) / NT;
    int sage_blk = (n_nodes + 15) / 16;  // 3125

    // CSR build (parallel scan)
    zero_i32<<<nb, NT, 0, stream>>>(cnt, n_nodes);
    hist_dst<<<eblk, NT, 0, stream>>>(cnt, dst, n_edges);
    scan_blocks<<<nb, NT, 0, stream>>>(cnt, bsum, n_nodes);
    scan_bsum<<<1, 1024, 0, stream>>>(bsum, boff, nb, row_off, n_nodes);
    scan_final<<<nb, NT, 0, stream>>>(cnt, boff, row_off, cursor, n_nodes);
    edge_scatter<<<eblk, NT, 0, stream>>>(csr_src, cursor, src, dst, n_edges);

    // prep: bf16 x, packed weights, pool init
    f2bf_kern<<<(int)((nfeat + NT - 1) / NT), NT, 0, stream>>>(bfX, x, (int)nfeat);
    pack_w<<<32, NT, 0, stream>>>(pw0, Wl0, Wr0);
    pack_w<<<32, NT, 0, stream>>>(pw, Wl, Wr);
    pool_init<<<(128 * 64 + NT - 1) / NT, NT, 0, stream>>>(pooled, 128 * 64);

    // layers (all-bf16 inter-layer state)
    sage_layer<<<sage_blk, NTS, 0, stream>>>(bfA, pooled, bfX, row_off, csr_src,
                                             batch, pw0, bl0, n_nodes, n_edges, 0);
    sage_layer<<<sage_blk, NTS, 0, stream>>>(bfB, pooled, bfA, row_off, csr_src,
                                             batch, pw, bl, n_nodes, n_edges, 0);
    sage_layer<<<sage_blk, NTS, 0, stream>>>(bfA, pooled, bfB, row_off, csr_src,
                                             batch, pw, bl, n_nodes, n_edges, 0);
    sage_layer<<<sage_blk, NTS, 0, stream>>>(bfB, pooled, bfA, row_off, csr_src,
                                             batch, pw, bl, n_nodes, n_edges, 1);

    head<<<32, NT, 0, stream>>>((float*)d_out, pooled, W1, b1, W2, b2);
}

// Round 23
// 399.680 us; speedup vs baseline: 1.5901x; 1.5901x over previous
//
#include <hip/hip_runtime.h>
#include <math.h>

#define NT 256
#define NTS 128   // sage_layer: 2 waves, 16-node tile

typedef unsigned short ushort_t;
typedef unsigned int uint_t;
typedef __attribute__((ext_vector_type(8))) short bf16x8;
typedef __attribute__((ext_vector_type(4))) float f32x4;

__device__ __forceinline__ int rli(int v, int l) {
    return __builtin_amdgcn_readlane(v, l);
}
__device__ __forceinline__ int imax(int a, int b) { return a > b ? a : b; }
__device__ __forceinline__ int imin(int a, int b) { return a < b ? a : b; }

__device__ __forceinline__ ushort_t f2bf_rne(float f) {
    uint_t u = __float_as_uint(f);
    uint_t r = u + 0x7FFF + ((u >> 16) & 1);
    return (ushort_t)(r >> 16);
}
__device__ __forceinline__ float bf2f(ushort_t b) {
    return __uint_as_float(((uint_t)b) << 16);
}
__device__ __forceinline__ float rlf(float v, int l) {
    return __int_as_float(__builtin_amdgcn_readlane(__float_as_int(v), l));
}

// ---------------- CSR build ----------------

__global__ void zero_i32(int* __restrict__ p, int n) {
    int t = blockIdx.x * blockDim.x + threadIdx.x;
    if (t < n) p[t] = 0;
}

__global__ void hist_dst(int* __restrict__ cnt, const int* __restrict__ dst, int n_edges) {
    int e = blockIdx.x * blockDim.x + threadIdx.x;
    if (e < n_edges) atomicAdd(&cnt[dst[e]], 1);
}

__global__ void scan_blocks(const int* __restrict__ cnt, int* __restrict__ bsum, int n) {
    __shared__ int s[NT];
    int i = blockIdx.x * NT + threadIdx.x;
    s[threadIdx.x] = (i < n) ? cnt[i] : 0;
    __syncthreads();
    for (int off = NT / 2; off > 0; off >>= 1) {
        if (threadIdx.x < off) s[threadIdx.x] += s[threadIdx.x + off];
        __syncthreads();
    }
    if (threadIdx.x == 0) bsum[blockIdx.x] = s[0];
}

__global__ void scan_bsum(const int* __restrict__ bsum, int* __restrict__ boff,
                          int nb, int* __restrict__ row_off, int n) {
    __shared__ int s[1024];
    int tid = threadIdx.x;
    int v = (tid < nb) ? bsum[tid] : 0;
    s[tid] = v;
    __syncthreads();
    for (int off = 1; off < 1024; off <<= 1) {
        int t = (tid >= off) ? s[tid - off] : 0;
        __syncthreads();
        s[tid] += t;
        __syncthreads();
    }
    if (tid < nb) boff[tid] = s[tid] - v;
    if (tid == nb - 1) row_off[n] = s[tid];
}

__global__ void scan_final(const int* __restrict__ cnt, const int* __restrict__ boff,
                           int* __restrict__ row_off, int* __restrict__ cursor, int n) {
    __shared__ int s[NT];
    int i = blockIdx.x * NT + threadIdx.x;
    int v = (i < n) ? cnt[i] : 0;
    s[threadIdx.x] = v;
    __syncthreads();
    for (int off = 1; off < NT; off <<= 1) {
        int t = (threadIdx.x >= off) ? s[threadIdx.x - off] : 0;
        __syncthreads();
        s[threadIdx.x] += t;
        __syncthreads();
    }
    if (i < n) {
        int ex = boff[blockIdx.x] + s[threadIdx.x] - v;
        row_off[i] = ex;
        cursor[i] = ex;
    }
}

__global__ void edge_scatter(int* __restrict__ csr_src, int* __restrict__ cursor,
                             const int* __restrict__ src, const int* __restrict__ dst,
                             int n_edges) {
    int e = blockIdx.x * blockDim.x + threadIdx.x;
    if (e < n_edges) {
        int p = atomicAdd(&cursor[dst[e]], 1);
        csr_src[p] = src[e];
    }
}

// ---------------- prep kernels ----------------

__global__ void f2bf_kern(ushort_t* __restrict__ o, const float* __restrict__ in, int n) {
    int t = blockIdx.x * blockDim.x + threadIdx.x;
    if (t < n) o[t] = f2bf_rne(in[t]);
}

// Pack combined weights into MFMA B-fragment order, bf16 (see r18).
__global__ void pack_w(ushort_t* __restrict__ packed, const float* __restrict__ Wl,
                       const float* __restrict__ Wr) {
    int t = blockIdx.x * blockDim.x + threadIdx.x;
    if (t < 8192) {
        int i = t & 7;
        int lane = (t >> 3) & 63;
        int nt = (t >> 9) & 3;
        int ks = t >> 11;
        int k = ks * 32 + ((lane >> 4) << 3) + i;
        int f = nt * 16 + (lane & 15);
        float w = (k < 64) ? Wl[f * 64 + k] : Wr[f * 64 + (k - 64)];
        packed[t] = f2bf_rne(w);
    }
}

// ---------------- pooling helpers ----------------

__global__ void pool_init(float* __restrict__ pooled, int n) {
    int t = blockIdx.x * blockDim.x + threadIdx.x;
    if (t < n) pooled[t] = -INFINITY;
}

__device__ __forceinline__ void atomicMaxFloat(float* addr, float value) {
    if (value >= 0.0f)
        atomicMax((int*)addr, __float_as_int(value));
    else
        atomicMin((unsigned int*)addr, (unsigned int)__float_as_int(value));
}

// ---------------- fused SAGE layer: 2-edges-per-load gather + MFMA dense ----------------
// Block = 128 thr = 2 waves = 16 nodes. Gather: a bf16 row is 128B, so one
// uint load per lane with lanes 0-31 on edge A's row and 32-63 on edge B's
// row fetches TWO edges per instruction -> 8-load groups cover 16 edges
// (vs 8), halving serialized latency-groups per node (ceil(d/16) vs
// ceil(d/8)). Cross-half combine via shfl_xor(32). Dense: r20 MFMA verbatim.
__global__ __launch_bounds__(NTS, 8) void sage_layer(
    ushort_t* __restrict__ out_bf, float* __restrict__ pooled,
    const ushort_t* __restrict__ hb_in,
    const int* __restrict__ row_off, const int* __restrict__ csr_src,
    const int* __restrict__ batch,
    const ushort_t* __restrict__ pw,
    const float* __restrict__ bl,
    int n_nodes, int do_pool) {
    __shared__ ushort_t A[16 * 136];
    int tid = threadIdx.x;
    int lane = tid & 63;
    int v = tid >> 6;  // wave 0..1
    int g0 = blockIdx.x * 16 + v * 8;
    int l31 = lane & 31;
    int h = lane >> 5;  // half-wave: 0 -> edge A, 1 -> edge B
    const uint_t* hb32 = (const uint_t*)hb_in;

    int roidx = imin(g0 + imin(lane, 8), n_nodes);
    int ro = row_off[roidx];

#pragma unroll
    for (int n = 0; n < 8; ++n) {
        int g = g0 + n;
        int row = v * 8 + n;
        int b = rli(ro, n);
        int e_ = rli(ro, n + 1);
        int d = e_ - b;
        bool ok = g < n_nodes;

        // hv row (cols 64-127)
        A[row * 136 + 64 + lane] = ok ? hb_in[((size_t)g << 6) + lane] : (ushort_t)0;

        if (ok && d <= 64) {
            // idx vector covering this node's edges (lane-clamped)
            int idx = csr_src[b + (lane < d ? lane : imax(d - 1, 0))];
            float accLo = 0.f, accHi = 0.f;
            for (int jj = 0; jj < d; jj += 16) {
                uint_t w0, w1, w2, w3, w4, w5, w6, w7;
#define LD(L, W)                                                              \
                {                                                             \
                    int eA = imin(jj + 2 * (L), d - 1);                       \
                    int eB = imin(jj + 2 * (L) + 1, d - 1);                   \
                    int iA = rli(idx, eA);                                    \
                    int iB = rli(idx, eB);                                    \
                    int is = (lane < 32) ? iA : iB;                           \
                    W = hb32[((size_t)(unsigned)is << 5) + l31];              \
                }
                LD(0, w0) LD(1, w1) LD(2, w2) LD(3, w3)
                LD(4, w4) LD(5, w5) LD(6, w6) LD(7, w7)
#undef LD
#define CS(L, W)                                                              \
                {                                                             \
                    float f = ((jj + 2 * (L) + h) < d) ? 1.f : 0.f;           \
                    accLo += f * __uint_as_float((W) << 16);                  \
                    accHi += f * __uint_as_float((W) & 0xffff0000u);          \
                }
                CS(0, w0) CS(1, w1) CS(2, w2) CS(3, w3)
                CS(4, w4) CS(5, w5) CS(6, w6) CS(7, w7)
#undef CS
            }
            // combine halves (A-edges + B-edges)
            accLo += __shfl_xor(accLo, 32);
            accHi += __shfl_xor(accHi, 32);
            float inv = 1.0f / (float)imax(d, 1);
            if (lane < 32) {
                uint_t mw = (uint_t)f2bf_rne(accLo * inv) |
                            ((uint_t)f2bf_rne(accHi * inv) << 16);
                *(uint_t*)&A[row * 136 + 2 * l31] = mw;
            }
        } else if (ok) {
            // slow path: deg > 64, chunked per-lane (feature = lane)
            float aa = 0.f;
            for (int cb = b; cb < e_; cb += 64) {
                int m = e_ - cb; if (m > 64) m = 64;
                int lidx = cb + (lane < m ? lane : m - 1);
                int idx2 = csr_src[lidx];
                for (int j = 0; j < m; ++j)
                    aa += bf2f(hb_in[((size_t)(unsigned)rli(idx2, j) << 6) + lane]);
            }
            A[row * 136 + lane] = f2bf_rne(aa * (1.0f / (float)imax(d, 1)));
        } else {
            A[row * 136 + lane] = 0;
        }
    }
    __syncthreads();

    // ---- phase 2: MFMA dense (r20 verbatim) ----
    int a_row = lane & 15;
    int kbase = (lane >> 4) << 3;
#pragma unroll
    for (int p = 0; p < 2; ++p) {
        int nt = v * 2 + p;
        f32x4 acc = {0.f, 0.f, 0.f, 0.f};
#pragma unroll
        for (int ks = 0; ks < 4; ++ks) {
            bf16x8 af = *reinterpret_cast<const bf16x8*>(&A[a_row * 136 + ks * 32 + kbase]);
            bf16x8 bf = *reinterpret_cast<const bf16x8*>(&pw[(((ks << 2) + nt) * 64 + lane) << 3]);
            acc = __builtin_amdgcn_mfma_f32_16x16x32_bf16(af, bf, acc, 0, 0, 0);
        }
        int c = nt * 16 + (lane & 15);
        float bias = bl[c];
        int rbase = blockIdx.x * 16 + ((lane >> 4) << 2);
#pragma unroll
        for (int j = 0; j < 4; ++j) {
            int g = rbase + j;
            if (g < n_nodes) {
                float o = tanhf(acc[j] + bias);
                if (do_pool) {
                    atomicMaxFloat(&pooled[(size_t)batch[g] * 64 + c], o);
                } else {
                    out_bf[(size_t)g * 64 + c] = f2bf_rne(o);
                }
            }
        }
    }
}

// ---------------- MLP head ----------------
__global__ void head(float* __restrict__ out, const float* __restrict__ pooled,
                     const float* __restrict__ W1, const float* __restrict__ b1,
                     const float* __restrict__ W2, const float* __restrict__ b2) {
    __shared__ float W1T[64][64];
    int tid = threadIdx.x;
    for (int t = tid; t < 4096; t += NT) {
        int f = t >> 6, k = t & 63;
        W1T[k][f] = W1[t];
    }
    __syncthreads();

    int lane = tid & 63;
    int g = blockIdx.x * (NT >> 6) + (tid >> 6);
    float v = pooled[(size_t)g * 64 + lane];
    float bias = b1[lane];
#pragma unroll
    for (int it = 0; it < 3; ++it) {
        float acc = bias;
#pragma unroll
        for (int k = 0; k < 64; ++k) {
            acc += rlf(v, k) * W1T[k][lane];
        }
        v = tanhf(acc);
    }
#pragma unroll
    for (int j = 0; j < 3; ++j) {
        float p = v * W2[j * 64 + lane];
#pragma unroll
        for (int off = 32; off >= 1; off >>= 1) p += __shfl_xor(p, off);
        if (lane == 0) out[g * 3 + j] = p + b2[j];
    }
}

// ---------------- launch ----------------

extern "C" void kernel_launch(void* const* d_in, const int* in_sizes, int n_in,
                              void* d_out, int out_size, void* d_ws, size_t ws_size,
                              hipStream_t stream) {
    const float* x   = (const float*)d_in[0];
    const float* Wl0 = (const float*)d_in[1];
    const float* Wr0 = (const float*)d_in[2];
    const float* bl0 = (const float*)d_in[3];
    const float* Wl  = (const float*)d_in[4];
    const float* Wr  = (const float*)d_in[5];
    const float* bl  = (const float*)d_in[6];
    const float* W1  = (const float*)d_in[7];
    const float* b1  = (const float*)d_in[8];
    const float* W2  = (const float*)d_in[9];
    const float* b2  = (const float*)d_in[10];
    const int* ei    = (const int*)d_in[11];
    const int* batch = (const int*)d_in[12];

    int n_nodes = in_sizes[0] / 64;
    int n_edges = in_sizes[11] / 2;
    const int* src = ei;
    const int* dst = ei + n_edges;

    int nb = (n_nodes + NT - 1) / NT;
    size_t nfeat = (size_t)n_nodes * 64;

    int* csr_src  = (int*)d_ws;                           // n_edges
    int* row_off  = csr_src + n_edges;                    // n_nodes+1
    int* cursor   = row_off + (n_nodes + 1);              // n_nodes
    int* cnt      = cursor + n_nodes;                     // n_nodes
    int* bsum     = cnt + n_nodes;                        // nb
    int* boff     = bsum + nb;                            // nb
    float* pooled = (float*)(boff + nb);                  // 128*64
    ushort_t* pw0 = (ushort_t*)(pooled + 128 * 64);       // 8192
    ushort_t* pw  = pw0 + 8192;                           // 8192
    ushort_t* bfX = pw + 8192;                            // nfeat
    ushort_t* bfA = bfX + nfeat;                          // nfeat
    ushort_t* bfB = bfA + nfeat;                          // nfeat

    int eblk = (n_edges + NT - 1) / NT;
    int sage_blk = (n_nodes + 15) / 16;  // 3125

    // CSR build (parallel scan)
    zero_i32<<<nb, NT, 0, stream>>>(cnt, n_nodes);
    hist_dst<<<eblk, NT, 0, stream>>>(cnt, dst, n_edges);
    scan_blocks<<<nb, NT, 0, stream>>>(cnt, bsum, n_nodes);
    scan_bsum<<<1, 1024, 0, stream>>>(bsum, boff, nb, row_off, n_nodes);
    scan_final<<<nb, NT, 0, stream>>>(cnt, boff, row_off, cursor, n_nodes);
    edge_scatter<<<eblk, NT, 0, stream>>>(csr_src, cursor, src, dst, n_edges);

    // prep: bf16 x, packed weights, pool init
    f2bf_kern<<<(int)((nfeat + NT - 1) / NT), NT, 0, stream>>>(bfX, x, (int)nfeat);
    pack_w<<<32, NT, 0, stream>>>(pw0, Wl0, Wr0);
    pack_w<<<32, NT, 0, stream>>>(pw, Wl, Wr);
    pool_init<<<(128 * 64 + NT - 1) / NT, NT, 0, stream>>>(pooled, 128 * 64);

    // layers (all-bf16 inter-layer state)
    sage_layer<<<sage_blk, NTS, 0, stream>>>(bfA, pooled, bfX, row_off, csr_src,
                                             batch, pw0, bl0, n_nodes, 0);
    sage_layer<<<sage_blk, NTS, 0, stream>>>(bfB, pooled, bfA, row_off, csr_src,
                                             batch, pw, bl, n_nodes, 0);
    sage_layer<<<sage_blk, NTS, 0, stream>>>(bfA, pooled, bfB, row_off, csr_src,
                                             batch, pw, bl, n_nodes, 0);
    sage_layer<<<sage_blk, NTS, 0, stream>>>(bfB, pooled, bfA, row_off, csr_src,
                                             batch, pw, bl, n_nodes, 1);

    head<<<32, NT, 0, stream>>>((float*)d_out, pooled, W1, b1, W2, b2);
}

// Round 24
// 381.219 us; speedup vs baseline: 1.6671x; 1.0484x over previous
//
#include <hip/hip_runtime.h>
#include <math.h>

#define NT 256
#define NTS 128   // sage_layer: 2 waves, 16-node tile

typedef unsigned short ushort_t;
typedef unsigned int uint_t;
typedef __attribute__((ext_vector_type(8))) short bf16x8;
typedef __attribute__((ext_vector_type(4))) float f32x4;

__device__ __forceinline__ int rli(int v, int l) {
    return __builtin_amdgcn_readlane(v, l);
}
__device__ __forceinline__ int imax(int a, int b) { return a > b ? a : b; }
__device__ __forceinline__ int imin(int a, int b) { return a < b ? a : b; }

__device__ __forceinline__ ushort_t f2bf_rne(float f) {
    uint_t u = __float_as_uint(f);
    uint_t r = u + 0x7FFF + ((u >> 16) & 1);
    return (ushort_t)(r >> 16);
}
__device__ __forceinline__ float bf2f(ushort_t b) {
    return __uint_as_float(((uint_t)b) << 16);
}
__device__ __forceinline__ float rlf(float v, int l) {
    return __int_as_float(__builtin_amdgcn_readlane(__float_as_int(v), l));
}

// ---------------- CSR build ----------------

__global__ void zero_i32(int* __restrict__ p, int n) {
    int t = blockIdx.x * blockDim.x + threadIdx.x;
    if (t < n) p[t] = 0;
}

__global__ void hist_dst(int* __restrict__ cnt, const int* __restrict__ dst, int n_edges) {
    int e = blockIdx.x * blockDim.x + threadIdx.x;
    if (e < n_edges) atomicAdd(&cnt[dst[e]], 1);
}

__global__ void scan_blocks(const int* __restrict__ cnt, int* __restrict__ bsum, int n) {
    __shared__ int s[NT];
    int i = blockIdx.x * NT + threadIdx.x;
    s[threadIdx.x] = (i < n) ? cnt[i] : 0;
    __syncthreads();
    for (int off = NT / 2; off > 0; off >>= 1) {
        if (threadIdx.x < off) s[threadIdx.x] += s[threadIdx.x + off];
        __syncthreads();
    }
    if (threadIdx.x == 0) bsum[blockIdx.x] = s[0];
}

__global__ void scan_bsum(const int* __restrict__ bsum, int* __restrict__ boff,
                          int nb, int* __restrict__ row_off, int n) {
    __shared__ int s[1024];
    int tid = threadIdx.x;
    int v = (tid < nb) ? bsum[tid] : 0;
    s[tid] = v;
    __syncthreads();
    for (int off = 1; off < 1024; off <<= 1) {
        int t = (tid >= off) ? s[tid - off] : 0;
        __syncthreads();
        s[tid] += t;
        __syncthreads();
    }
    if (tid < nb) boff[tid] = s[tid] - v;
    if (tid == nb - 1) row_off[n] = s[tid];
}

__global__ void scan_final(const int* __restrict__ cnt, const int* __restrict__ boff,
                           int* __restrict__ row_off, int* __restrict__ cursor, int n) {
    __shared__ int s[NT];
    int i = blockIdx.x * NT + threadIdx.x;
    int v = (i < n) ? cnt[i] : 0;
    s[threadIdx.x] = v;
    __syncthreads();
    for (int off = 1; off < NT; off <<= 1) {
        int t = (threadIdx.x >= off) ? s[threadIdx.x - off] : 0;
        __syncthreads();
        s[threadIdx.x] += t;
        __syncthreads();
    }
    if (i < n) {
        int ex = boff[blockIdx.x] + s[threadIdx.x] - v;
        row_off[i] = ex;
        cursor[i] = ex;
    }
}

__global__ void edge_scatter(int* __restrict__ csr_src, int* __restrict__ cursor,
                             const int* __restrict__ src, const int* __restrict__ dst,
                             int n_edges) {
    int e = blockIdx.x * blockDim.x + threadIdx.x;
    if (e < n_edges) {
        int p = atomicAdd(&cursor[dst[e]], 1);
        csr_src[p] = src[e];
    }
}

// ---------------- prep kernels ----------------

__global__ void f2bf_kern(ushort_t* __restrict__ o, const float* __restrict__ in, int n) {
    int t = blockIdx.x * blockDim.x + threadIdx.x;
    if (t < n) o[t] = f2bf_rne(in[t]);
}

// Pack combined weights into MFMA B-fragment order, bf16 (see r18).
__global__ void pack_w(ushort_t* __restrict__ packed, const float* __restrict__ Wl,
                       const float* __restrict__ Wr) {
    int t = blockIdx.x * blockDim.x + threadIdx.x;
    if (t < 8192) {
        int i = t & 7;
        int lane = (t >> 3) & 63;
        int nt = (t >> 9) & 3;
        int ks = t >> 11;
        int k = ks * 32 + ((lane >> 4) << 3) + i;
        int f = nt * 16 + (lane & 15);
        float w = (k < 64) ? Wl[f * 64 + k] : Wr[f * 64 + (k - 64)];
        packed[t] = f2bf_rne(w);
    }
}

// ---------------- pooling helpers ----------------

__global__ void pool_init(float* __restrict__ pooled, int n) {
    int t = blockIdx.x * blockDim.x + threadIdx.x;
    if (t < n) pooled[t] = -INFINITY;
}

__device__ __forceinline__ void atomicMaxFloat(float* addr, float value) {
    if (value >= 0.0f)
        atomicMax((int*)addr, __float_as_int(value));
    else
        atomicMin((unsigned int*)addr, (unsigned int)__float_as_int(value));
}

// ---------------- fused SAGE layer: hoisted-idx gather + MFMA dense ----------------
// Block = 128 thr = 2 waves = 16 nodes. ALL 8 idx-vector loads and 8 hv-row
// loads are hoisted to the wave prologue (16 independent loads in flight
// before first consume) -- removes the per-node serialized idx-load latency
// that headed every node's chain in r20/r23. Gather: 2 edges per uint load
// (lanes 0-31 edge A, 32-63 edge B; combine via shfl_xor(32)). Dense: r20
// MFMA verbatim.
__global__ __launch_bounds__(NTS, 8) void sage_layer(
    ushort_t* __restrict__ out_bf, float* __restrict__ pooled,
    const ushort_t* __restrict__ hb_in,
    const int* __restrict__ row_off, const int* __restrict__ csr_src,
    const int* __restrict__ batch,
    const ushort_t* __restrict__ pw,
    const float* __restrict__ bl,
    int n_nodes, int do_pool) {
    __shared__ ushort_t A[16 * 136];
    int tid = threadIdx.x;
    int lane = tid & 63;
    int v = tid >> 6;  // wave 0..1
    int g0 = blockIdx.x * 16 + v * 8;
    int l31 = lane & 31;
    int h = lane >> 5;  // half-wave: 0 -> edge A, 1 -> edge B
    const uint_t* hb32 = (const uint_t*)hb_in;

    int roidx = imin(g0 + imin(lane, 8), n_nodes);
    int ro = row_off[roidx];

    // broadcast row bounds for the 8 nodes
    int b0 = rli(ro, 0), b1 = rli(ro, 1), b2 = rli(ro, 2), b3 = rli(ro, 3);
    int b4 = rli(ro, 4), b5 = rli(ro, 5), b6 = rli(ro, 6), b7 = rli(ro, 7);
    int e8 = rli(ro, 8);
    int d0 = b1 - b0, d1 = b2 - b1, d2 = b3 - b2, d3 = b4 - b3;
    int d4 = b5 - b4, d5 = b6 - b5, d6 = b7 - b6, d7 = e8 - b7;

    // ---- hoisted independent loads: 8 idx vectors + 8 hv rows ----
#define IDXLD(N) int idx##N = csr_src[b##N + (lane < d##N ? lane : imax(d##N - 1, 0))];
    IDXLD(0) IDXLD(1) IDXLD(2) IDXLD(3) IDXLD(4) IDXLD(5) IDXLD(6) IDXLD(7)
#undef IDXLD
#define HVLD(N) ushort_t hv##N = (g0 + (N) < n_nodes) \
        ? hb_in[((size_t)(g0 + (N)) << 6) + lane] : (ushort_t)0;
    HVLD(0) HVLD(1) HVLD(2) HVLD(3) HVLD(4) HVLD(5) HVLD(6) HVLD(7)
#undef HVLD
    // stage hv rows (cols 64-127)
    {
        int rb = v * 8;
        A[(rb + 0) * 136 + 64 + lane] = hv0;
        A[(rb + 1) * 136 + 64 + lane] = hv1;
        A[(rb + 2) * 136 + 64 + lane] = hv2;
        A[(rb + 3) * 136 + 64 + lane] = hv3;
        A[(rb + 4) * 136 + 64 + lane] = hv4;
        A[(rb + 5) * 136 + 64 + lane] = hv5;
        A[(rb + 6) * 136 + 64 + lane] = hv6;
        A[(rb + 7) * 136 + 64 + lane] = hv7;
    }

    // ---- per-node gather from pre-loaded indices ----
#define GATHER(N)                                                             \
    {                                                                         \
        int row = v * 8 + (N);                                                \
        int d = d##N;                                                         \
        bool ok = (g0 + (N)) < n_nodes;                                       \
        if (ok && d <= 64) {                                                  \
            float accLo = 0.f, accHi = 0.f;                                   \
            for (int jj = 0; jj < d; jj += 16) {                              \
                uint_t w0, w1, w2, w3, w4, w5, w6, w7;                        \
                { int eA = imin(jj + 0, d - 1), eB = imin(jj + 1, d - 1);     \
                  int is = (lane < 32) ? rli(idx##N, eA) : rli(idx##N, eB);   \
                  w0 = hb32[((size_t)(unsigned)is << 5) + l31]; }             \
                { int eA = imin(jj + 2, d - 1), eB = imin(jj + 3, d - 1);     \
                  int is = (lane < 32) ? rli(idx##N, eA) : rli(idx##N, eB);   \
                  w1 = hb32[((size_t)(unsigned)is << 5) + l31]; }             \
                { int eA = imin(jj + 4, d - 1), eB = imin(jj + 5, d - 1);     \
                  int is = (lane < 32) ? rli(idx##N, eA) : rli(idx##N, eB);   \
                  w2 = hb32[((size_t)(unsigned)is << 5) + l31]; }             \
                { int eA = imin(jj + 6, d - 1), eB = imin(jj + 7, d - 1);     \
                  int is = (lane < 32) ? rli(idx##N, eA) : rli(idx##N, eB);   \
                  w3 = hb32[((size_t)(unsigned)is << 5) + l31]; }             \
                { int eA = imin(jj + 8, d - 1), eB = imin(jj + 9, d - 1);     \
                  int is = (lane < 32) ? rli(idx##N, eA) : rli(idx##N, eB);   \
                  w4 = hb32[((size_t)(unsigned)is << 5) + l31]; }             \
                { int eA = imin(jj + 10, d - 1), eB = imin(jj + 11, d - 1);   \
                  int is = (lane < 32) ? rli(idx##N, eA) : rli(idx##N, eB);   \
                  w5 = hb32[((size_t)(unsigned)is << 5) + l31]; }             \
                { int eA = imin(jj + 12, d - 1), eB = imin(jj + 13, d - 1);   \
                  int is = (lane < 32) ? rli(idx##N, eA) : rli(idx##N, eB);   \
                  w6 = hb32[((size_t)(unsigned)is << 5) + l31]; }             \
                { int eA = imin(jj + 14, d - 1), eB = imin(jj + 15, d - 1);   \
                  int is = (lane < 32) ? rli(idx##N, eA) : rli(idx##N, eB);   \
                  w7 = hb32[((size_t)(unsigned)is << 5) + l31]; }             \
                { float f = ((jj + 0 + h) < d) ? 1.f : 0.f;                   \
                  accLo += f * __uint_as_float(w0 << 16);                     \
                  accHi += f * __uint_as_float(w0 & 0xffff0000u); }           \
                { float f = ((jj + 2 + h) < d) ? 1.f : 0.f;                   \
                  accLo += f * __uint_as_float(w1 << 16);                     \
                  accHi += f * __uint_as_float(w1 & 0xffff0000u); }           \
                { float f = ((jj + 4 + h) < d) ? 1.f : 0.f;                   \
                  accLo += f * __uint_as_float(w2 << 16);                     \
                  accHi += f * __uint_as_float(w2 & 0xffff0000u); }           \
                { float f = ((jj + 6 + h) < d) ? 1.f : 0.f;                   \
                  accLo += f * __uint_as_float(w3 << 16);                     \
                  accHi += f * __uint_as_float(w3 & 0xffff0000u); }           \
                { float f = ((jj + 8 + h) < d) ? 1.f : 0.f;                   \
                  accLo += f * __uint_as_float(w4 << 16);                     \
                  accHi += f * __uint_as_float(w4 & 0xffff0000u); }           \
                { float f = ((jj + 10 + h) < d) ? 1.f : 0.f;                  \
                  accLo += f * __uint_as_float(w5 << 16);                     \
                  accHi += f * __uint_as_float(w5 & 0xffff0000u); }           \
                { float f = ((jj + 12 + h) < d) ? 1.f : 0.f;                  \
                  accLo += f * __uint_as_float(w6 << 16);                     \
                  accHi += f * __uint_as_float(w6 & 0xffff0000u); }           \
                { float f = ((jj + 14 + h) < d) ? 1.f : 0.f;                  \
                  accLo += f * __uint_as_float(w7 << 16);                     \
                  accHi += f * __uint_as_float(w7 & 0xffff0000u); }           \
            }                                                                 \
            accLo += __shfl_xor(accLo, 32);                                   \
            accHi += __shfl_xor(accHi, 32);                                   \
            float inv = 1.0f / (float)imax(d, 1);                             \
            if (lane < 32) {                                                  \
                uint_t mw = (uint_t)f2bf_rne(accLo * inv) |                   \
                            ((uint_t)f2bf_rne(accHi * inv) << 16);            \
                *(uint_t*)&A[row * 136 + 2 * l31] = mw;                       \
            }                                                                 \
        } else if (ok) {                                                      \
            float aa = 0.f;                                                   \
            int b = b##N, e_ = b##N + d;                                      \
            for (int cb = b; cb < e_; cb += 64) {                             \
                int m = e_ - cb; if (m > 64) m = 64;                          \
                int lidx = cb + (lane < m ? lane : m - 1);                    \
                int idx2 = csr_src[lidx];                                     \
                for (int j = 0; j < m; ++j)                                   \
                    aa += bf2f(hb_in[((size_t)(unsigned)rli(idx2, j) << 6) + lane]); \
            }                                                                 \
            A[row * 136 + lane] = f2bf_rne(aa * (1.0f / (float)imax(d, 1)));  \
        } else {                                                              \
            A[row * 136 + lane] = 0;                                          \
        }                                                                     \
    }
    GATHER(0) GATHER(1) GATHER(2) GATHER(3)
    GATHER(4) GATHER(5) GATHER(6) GATHER(7)
#undef GATHER
    __syncthreads();

    // ---- phase 2: MFMA dense (r20 verbatim) ----
    int a_row = lane & 15;
    int kbase = (lane >> 4) << 3;
#pragma unroll
    for (int p = 0; p < 2; ++p) {
        int nt = v * 2 + p;
        f32x4 acc = {0.f, 0.f, 0.f, 0.f};
#pragma unroll
        for (int ks = 0; ks < 4; ++ks) {
            bf16x8 af = *reinterpret_cast<const bf16x8*>(&A[a_row * 136 + ks * 32 + kbase]);
            bf16x8 bf = *reinterpret_cast<const bf16x8*>(&pw[(((ks << 2) + nt) * 64 + lane) << 3]);
            acc = __builtin_amdgcn_mfma_f32_16x16x32_bf16(af, bf, acc, 0, 0, 0);
        }
        int c = nt * 16 + (lane & 15);
        float bias = bl[c];
        int rbase = blockIdx.x * 16 + ((lane >> 4) << 2);
#pragma unroll
        for (int j = 0; j < 4; ++j) {
            int g = rbase + j;
            if (g < n_nodes) {
                float o = tanhf(acc[j] + bias);
                if (do_pool) {
                    atomicMaxFloat(&pooled[(size_t)batch[g] * 64 + c], o);
                } else {
                    out_bf[(size_t)g * 64 + c] = f2bf_rne(o);
                }
            }
        }
    }
}

// ---------------- MLP head ----------------
__global__ void head(float* __restrict__ out, const float* __restrict__ pooled,
                     const float* __restrict__ W1, const float* __restrict__ b1,
                     const float* __restrict__ W2, const float* __restrict__ b2) {
    __shared__ float W1T[64][64];
    int tid = threadIdx.x;
    for (int t = tid; t < 4096; t += NT) {
        int f = t >> 6, k = t & 63;
        W1T[k][f] = W1[t];
    }
    __syncthreads();

    int lane = tid & 63;
    int g = blockIdx.x * (NT >> 6) + (tid >> 6);
    float v = pooled[(size_t)g * 64 + lane];
    float bias = b1[lane];
#pragma unroll
    for (int it = 0; it < 3; ++it) {
        float acc = bias;
#pragma unroll
        for (int k = 0; k < 64; ++k) {
            acc += rlf(v, k) * W1T[k][lane];
        }
        v = tanhf(acc);
    }
#pragma unroll
    for (int j = 0; j < 3; ++j) {
        float p = v * W2[j * 64 + lane];
#pragma unroll
        for (int off = 32; off >= 1; off >>= 1) p += __shfl_xor(p, off);
        if (lane == 0) out[g * 3 + j] = p + b2[j];
    }
}

// ---------------- launch ----------------

extern "C" void kernel_launch(void* const* d_in, const int* in_sizes, int n_in,
                              void* d_out, int out_size, void* d_ws, size_t ws_size,
                              hipStream_t stream) {
    const float* x   = (const float*)d_in[0];
    const float* Wl0 = (const float*)d_in[1];
    const float* Wr0 = (const float*)d_in[2];
    const float* bl0 = (const float*)d_in[3];
    const float* Wl  = (const float*)d_in[4];
    const float* Wr  = (const float*)d_in[5];
    const float* bl  = (const float*)d_in[6];
    const float* W1  = (const float*)d_in[7];
    const float* b1  = (const float*)d_in[8];
    const float* W2  = (const float*)d_in[9];
    const float* b2  = (const float*)d_in[10];
    const int* ei    = (const int*)d_in[11];
    const int* batch = (const int*)d_in[12];

    int n_nodes = in_sizes[0] / 64;
    int n_edges = in_sizes[11] / 2;
    const int* src = ei;
    const int* dst = ei + n_edges;

    int nb = (n_nodes + NT - 1) / NT;
    size_t nfeat = (size_t)n_nodes * 64;

    int* csr_src  = (int*)d_ws;                           // n_edges
    int* row_off  = csr_src + n_edges;                    // n_nodes+1
    int* cursor   = row_off + (n_nodes + 1);              // n_nodes
    int* cnt      = cursor + n_nodes;                     // n_nodes
    int* bsum     = cnt + n_nodes;                        // nb
    int* boff     = bsum + nb;                            // nb
    float* pooled = (float*)(boff + nb);                  // 128*64
    ushort_t* pw0 = (ushort_t*)(pooled + 128 * 64);       // 8192
    ushort_t* pw  = pw0 + 8192;                           // 8192
    ushort_t* bfX = pw + 8192;                            // nfeat
    ushort_t* bfA = bfX + nfeat;                          // nfeat
    ushort_t* bfB = bfA + nfeat;                          // nfeat

    int eblk = (n_edges + NT - 1) / NT;
    int sage_blk = (n_nodes + 15) / 16;  // 3125

    // CSR build (parallel scan)
    zero_i32<<<nb, NT, 0, stream>>>(cnt, n_nodes);
    hist_dst<<<eblk, NT, 0, stream>>>(cnt, dst, n_edges);
    scan_blocks<<<nb, NT, 0, stream>>>(cnt, bsum, n_nodes);
    scan_bsum<<<1, 1024, 0, stream>>>(bsum, boff, nb, row_off, n_nodes);
    scan_final<<<nb, NT, 0, stream>>>(cnt, boff, row_off, cursor, n_nodes);
    edge_scatter<<<eblk, NT, 0, stream>>>(csr_src, cursor, src, dst, n_edges);

    // prep: bf16 x, packed weights, pool init
    f2bf_kern<<<(int)((nfeat + NT - 1) / NT), NT, 0, stream>>>(bfX, x, (int)nfeat);
    pack_w<<<32, NT, 0, stream>>>(pw0, Wl0, Wr0);
    pack_w<<<32, NT, 0, stream>>>(pw, Wl, Wr);
    pool_init<<<(128 * 64 + NT - 1) / NT, NT, 0, stream>>>(pooled, 128 * 64);

    // layers (all-bf16 inter-layer state)
    sage_layer<<<sage_blk, NTS, 0, stream>>>(bfA, pooled, bfX, row_off, csr_src,
                                             batch, pw0, bl0, n_nodes, 0);
    sage_layer<<<sage_blk, NTS, 0, stream>>>(bfB, pooled, bfA, row_off, csr_src,
                                             batch, pw, bl, n_nodes, 0);
    sage_layer<<<sage_blk, NTS, 0, stream>>>(bfA, pooled, bfB, row_off, csr_src,
                                             batch, pw, bl, n_nodes, 0);
    sage_layer<<<sage_blk, NTS, 0, stream>>>(bfB, pooled, bfA, row_off, csr_src,
                                             batch, pw, bl, n_nodes, 1);

    head<<<32, NT, 0, stream>>>((float*)d_out, pooled, W1, b1, W2, b2);
}